// Round 1
// baseline (122.501 us; speedup 1.0000x reference)
//
#include <hip/hip_runtime.h>
#include <hip/hip_bf16.h>
#include <cstdint>

#define BB 512
#define NN 512
#define FF 512
#define DD 256
#define KTOP 10
#define BN (BB*NN)        // 262144 rows
#define BM 64             // rows per tile
#define NTILES (BN/BM)    // 4096
#define LDAP 264          // padded LDS row length in ushorts (528B, 16B-aligned)

typedef __attribute__((ext_vector_type(8))) short bf16x8;
typedef __attribute__((ext_vector_type(4))) short s16x4;
typedef __attribute__((ext_vector_type(4))) float f32x4;

__device__ __forceinline__ ushort f2bf(float x){
  uint32_t u = __float_as_uint(x);
  uint32_t r = (u + 0x7FFFu + ((u >> 16) & 1u)) >> 16;  // RNE
  return (ushort)r;
}
__device__ __forceinline__ float bf2f(ushort b){
  return __uint_as_float(((uint32_t)b) << 16);
}

// ---------------- kernel 0: W f32 -> bf16 ----------------
__global__ void wconv(const float* __restrict__ W, ushort* __restrict__ Wbf){
  int i = (blockIdx.x*256 + threadIdx.x)*4;   // 64 blocks * 256 thr * 4 = 65536
  float4 v = *reinterpret_cast<const float4*>(W + i);
  s16x4 o;
  o[0] = (short)f2bf(v.x); o[1] = (short)f2bf(v.y);
  o[2] = (short)f2bf(v.z); o[3] = (short)f2bf(v.w);
  *reinterpret_cast<s16x4*>(Wbf + i) = o;
}

// ---------------- kernel 1: fused GEMM + bilinear reduce ----------------
// score[m] = attn[m] * sum_e dis[m,e] * sum_d W[e,d] * drug[m,d]
__global__ __launch_bounds__(256, 2)
void score_kernel(const float* __restrict__ emb, const float* __restrict__ attn,
                  const ushort* __restrict__ Wbf, float* __restrict__ scores){
  __shared__ ushort Al[BM*LDAP];   // drug tile, bf16
  __shared__ ushort Sl[BM*LDAP];   // dis  tile, bf16
  __shared__ float red[4][BM];

  const int tid  = threadIdx.x;
  const int w    = tid >> 6;        // wave 0..3, owns e-range [w*64, w*64+64)
  const int lane = tid & 63;
  const int g    = lane >> 4;       // k-group / row-group
  const int c    = lane & 15;       // col-in-16

  // W B-fragments in registers: B[k][e] = W[e][k]. Lane l: e = base + c, k = kb*32 + g*8 .. +8
  bf16x8 Wf[4][8];
#pragma unroll
  for (int eb = 0; eb < 4; ++eb)
#pragma unroll
    for (int kb = 0; kb < 8; ++kb){
      int e = w*64 + eb*16 + c;
      int k = kb*32 + g*8;
      Wf[eb][kb] = *reinterpret_cast<const bf16x8*>(Wbf + e*DD + k);
    }

  const int ch = tid & 63;          // which 8-float chunk of a 512-float row
  const int rsub = tid >> 6;        // row sub-index for staging

  for (int tile = blockIdx.x; tile < NTILES; tile += gridDim.x){
    const float* base = emb + (size_t)tile * BM * FF;

    // ---- stage: 64 rows x 512 f32 -> bf16 LDS (drug | dis halves) ----
#pragma unroll
    for (int it = 0; it < 16; ++it){
      int row = it*4 + rsub;
      const float* src = base + row*FF + ch*8;
      float4 v0 = *reinterpret_cast<const float4*>(src);
      float4 v1 = *reinterpret_cast<const float4*>(src + 4);
      bf16x8 p;
      p[0]=(short)f2bf(v0.x); p[1]=(short)f2bf(v0.y); p[2]=(short)f2bf(v0.z); p[3]=(short)f2bf(v0.w);
      p[4]=(short)f2bf(v1.x); p[5]=(short)f2bf(v1.y); p[6]=(short)f2bf(v1.z); p[7]=(short)f2bf(v1.w);
      ushort* dst = (ch < 32) ? (Al + row*LDAP + ch*8)
                              : (Sl + row*LDAP + (ch-32)*8);
      *reinterpret_cast<bf16x8*>(dst) = p;
    }
    __syncthreads();

    // ---- compute ----
    for (int mb = 0; mb < 4; ++mb){
      const int m0 = mb*16;
      bf16x8 af[8];
#pragma unroll
      for (int kb = 0; kb < 8; ++kb)
        af[kb] = *reinterpret_cast<const bf16x8*>(Al + (m0 + c)*LDAP + kb*32 + g*8);
      float rs0=0.f, rs1=0.f, rs2=0.f, rs3=0.f;
#pragma unroll
      for (int eb = 0; eb < 4; ++eb){
        f32x4 acc = {0.f, 0.f, 0.f, 0.f};
#pragma unroll
        for (int kb = 0; kb < 8; ++kb)
          acc = __builtin_amdgcn_mfma_f32_16x16x32_bf16(af[kb], Wf[eb][kb], acc, 0, 0, 0);
        // C[m0+g*4+j][w*64+eb*16+c] in acc[j]; multiply by dis and accumulate
        const int e_loc = w*64 + eb*16 + c;
        rs0 += acc[0] * bf2f(Sl[(m0 + g*4 + 0)*LDAP + e_loc]);
        rs1 += acc[1] * bf2f(Sl[(m0 + g*4 + 1)*LDAP + e_loc]);
        rs2 += acc[2] * bf2f(Sl[(m0 + g*4 + 2)*LDAP + e_loc]);
        rs3 += acc[3] * bf2f(Sl[(m0 + g*4 + 3)*LDAP + e_loc]);
      }
      // reduce across the 16 c-lanes (same rows, different e columns)
      float r0=rs0, r1=rs1, r2=rs2, r3=rs3;
      r0 += __shfl_xor(r0,1); r0 += __shfl_xor(r0,2); r0 += __shfl_xor(r0,4); r0 += __shfl_xor(r0,8);
      r1 += __shfl_xor(r1,1); r1 += __shfl_xor(r1,2); r1 += __shfl_xor(r1,4); r1 += __shfl_xor(r1,8);
      r2 += __shfl_xor(r2,1); r2 += __shfl_xor(r2,2); r2 += __shfl_xor(r2,4); r2 += __shfl_xor(r2,8);
      r3 += __shfl_xor(r3,1); r3 += __shfl_xor(r3,2); r3 += __shfl_xor(r3,4); r3 += __shfl_xor(r3,8);
      if (c == 0){
        red[w][m0 + g*4 + 0] = r0;
        red[w][m0 + g*4 + 1] = r1;
        red[w][m0 + g*4 + 2] = r2;
        red[w][m0 + g*4 + 3] = r3;
      }
    }
    __syncthreads();
    if (tid < BM){
      int row = tile*BM + tid;
      float s = red[0][tid] + red[1][tid] + red[2][tid] + red[3][tid];
      scores[row] = attn[row] * s;
    }
    __syncthreads();   // protect LDS before next tile's staging
  }
}

// ---------------- kernel 2: per-batch top-K mean ----------------
__global__ void topk_kernel(const float* __restrict__ scores, float* __restrict__ out){
  const int b = blockIdx.x;
  const int lane = threadIdx.x;   // 64 threads
  float v0,v1,v2,v3,v4,v5,v6,v7;
  const float* s = scores + b*NN;
  v0=s[lane]; v1=s[64+lane]; v2=s[128+lane]; v3=s[192+lane];
  v4=s[256+lane]; v5=s[320+lane]; v6=s[384+lane]; v7=s[448+lane];
  float total = 0.f;
  for (int it = 0; it < KTOP; ++it){
    float m = v0; int mj = 0;
    if (v1>m){m=v1;mj=1;} if (v2>m){m=v2;mj=2;} if (v3>m){m=v3;mj=3;}
    if (v4>m){m=v4;mj=4;} if (v5>m){m=v5;mj=5;} if (v6>m){m=v6;mj=6;}
    if (v7>m){m=v7;mj=7;}
    float bm = m; int bl = lane;
#pragma unroll
    for (int off = 32; off; off >>= 1){
      float om = __shfl_xor(bm, off);
      int   ol = __shfl_xor(bl, off);
      if (om > bm || (om == bm && ol < bl)){ bm = om; bl = ol; }
    }
    total += bm;
    if (lane == bl){
      if (mj==0) v0=-3.0e38f; else if (mj==1) v1=-3.0e38f;
      else if (mj==2) v2=-3.0e38f; else if (mj==3) v3=-3.0e38f;
      else if (mj==4) v4=-3.0e38f; else if (mj==5) v5=-3.0e38f;
      else if (mj==6) v6=-3.0e38f; else v7=-3.0e38f;
    }
  }
  if (lane == 0) out[b] = total * (1.0f / KTOP);
}

extern "C" void kernel_launch(void* const* d_in, const int* in_sizes, int n_in,
                              void* d_out, int out_size, void* d_ws, size_t ws_size,
                              hipStream_t stream){
  const float* emb  = (const float*)d_in[0];   // (B,N,F) f32
  const float* attn = (const float*)d_in[1];   // (B,N,1) f32
  const float* W    = (const float*)d_in[2];   // (D,D) f32
  float* out = (float*)d_out;                  // (B,1) f32

  ushort* Wbf   = (ushort*)d_ws;                               // 128 KB
  float*  scores = (float*)((char*)d_ws + DD*DD*sizeof(ushort)); // 1 MB

  wconv<<<64, 256, 0, stream>>>(W, Wbf);
  score_kernel<<<512, 256, 0, stream>>>(emb, attn, Wbf, scores);
  topk_kernel<<<BB, 64, 0, stream>>>(scores, out);
}